// Round 6
// baseline (174.831 us; speedup 1.0000x reference)
//
#include <hip/hip_runtime.h>
#include <hip/hip_bf16.h>
#include <math.h>

#define B_  4
#define S_  2048
#define D_  512
#define H_  8
#define DK_ 64
#define M_  (B_ * S_)   // 8192

using bf16   = __bf16;
using bf16x4 = __bf16 __attribute__((ext_vector_type(4)));
using bf16x8 = __bf16 __attribute__((ext_vector_type(8)));
using f32x4  = float __attribute__((ext_vector_type(4)));

#define MFMA16(a, b, c) __builtin_amdgcn_mfma_f32_16x16x32_bf16((a), (b), (c), 0, 0, 0)
#define EXP2(x) exp2f(x)

typedef __attribute__((address_space(3))) void       lds_void;
typedef const __attribute__((address_space(1))) void gbl_void;

__device__ __forceinline__ void async16(const bf16* g, bf16* lds) {
    __builtin_amdgcn_global_load_lds((gbl_void*)g, (lds_void*)lds, 16, 0, 0);
}

__device__ __forceinline__ bf16x8 ldg8(const bf16* p) {
    return *reinterpret_cast<const bf16x8*>(p);
}

// Fragment-major layout for a [R x 512] matrix (rows = MFMA m/n dim, cols = K):
// chunk(g,k0,kk,t) holds rows g*64+t*16+{0..15}, cols k0*64+kk*32+{0..31};
// lane = (k_sub>>3)*16 + (row&15), 8 bf16 per lane. One ldg8 at base+lane*8 is
// a fully-coalesced 1 KB read in exact MFMA A/B fragment order.
__device__ __forceinline__ size_t fragbase(int g, int k0, int kk, int t) {
    return ((((size_t)(g * 8 + k0) * 2 + kk) * 4 + t) * 64) * 8;
}

// ---------------------------------------------------------------------------
// Fused f32->bf16 conversion + fragment-major re-layout for all 7 tensors.
// One WAVE per 1 KB fragment chunk: dst = base + c*512 + lane*8 is exactly
// linear (fully-coalesced 16 B/lane stores); src gathers 16 rows x 32 B
// (128 B-coalescible across the lg groups).
// ---------------------------------------------------------------------------
__global__ __launch_bounds__(256) void cvt_all(
    const float* __restrict__ x0, const float* __restrict__ x1, const float* __restrict__ x2,
    const float* __restrict__ w0, const float* __restrict__ w1,
    const float* __restrict__ w2, const float* __restrict__ w3,
    bf16* __restrict__ dst)
{
    const int w    = blockIdx.x * 4 + (threadIdx.x >> 6);  // wave id, 0..26623
    const int lane = threadIdx.x & 63;
    const int lg = lane >> 4, lc = lane & 15;
    const float* src;
    int c;
    size_t dbase;
    if (w < 24576) {                                       // X tensors: 3 x 8192 chunks
        const int seg = w >> 13;
        c = w & 8191;
        src = (seg == 0) ? x0 : (seg == 1) ? x1 : x2;
        dbase = (size_t)seg << 22;
    } else {                                               // W tensors: 4 x 512 chunks
        const int jj = w - 24576;
        const int seg = jj >> 9;
        c = jj & 511;
        src = (seg == 0) ? w0 : (seg == 1) ? w1 : (seg == 2) ? w2 : w3;
        dbase = ((size_t)3 << 22) + ((size_t)seg << 18);
    }
    // c = ((g*8+k0)*2+kk)*4+t  (matches fragbase ordering)
    const int g = c >> 6, k0 = (c >> 3) & 7, kk = (c >> 2) & 1, t = c & 3;
    const size_t soff = ((size_t)(g * 64 + t * 16 + lc) << 9) + k0 * 64 + kk * 32 + lg * 8;
    f32x4 a = *reinterpret_cast<const f32x4*>(src + soff);
    f32x4 b = *reinterpret_cast<const f32x4*>(src + soff + 4);
    bf16x8 r;
    #pragma unroll
    for (int j = 0; j < 4; ++j) { r[j] = (bf16)a[j]; r[j + 4] = (bf16)b[j]; }
    *reinterpret_cast<bf16x8*>(dst + dbase + ((size_t)c << 9) + (size_t)lane * 8) = r;
}

// ---------------------------------------------------------------------------
// QKV projection with LDS RING (r6): the old LDS-free k-loop issued 8
// dependent L2 loads per 16 MFMAs and was L2-latency-stalled at 12 waves/CU.
// Now: ring-3 LDS (48 KB), raw s_barrier + counted vmcnt(4) (T3/T4 pattern
// verified in attn r4/r5). Frag-major global layout => staging is a PURE
// LINEAR copy: each async16 moves one 1 KB fragment chunk (wave-uniform LDS
// base + lane*16B, per guide T21); ds_read_b128 back is conflict-free.
// Per kk-step: stage 16 KB/block (4 chunks/wave), each wave reads 8 frags,
// 16 MFMA. stage(s+2) after the barrier overwrites buf (s-1)%3 whose readers
// all crossed this barrier.
// z<2 (Q,K): A=W (m=d), B=X (n=s); z==0 folds 0.125*log2e. z==2 (V): V^T out.
// Grid 768 (3 blocks/CU = 12 waves/CU), XCD-affine mt decode.
// ---------------------------------------------------------------------------
__global__ __launch_bounds__(256) void gemm_qkv(
    const bf16* __restrict__ Xf, const bf16* __restrict__ Wf,
    bf16* __restrict__ qkv)
{
    const int bx  = blockIdx.x;
    const int xcd = bx & 7;
    const int idx = bx >> 3;
    const int mt  = xcd + 8 * (idx & 7);       // 0..63: X 128-row tile
    const int rest = idx >> 3;
    const int nt  = rest & 3;                  // 0..3: W 128-row tile
    const int z   = rest >> 2;                 // 0..2

    const bf16* Xz = Xf + (size_t)z * M_ * D_;
    const bf16* Wz = Wf + (size_t)z * D_ * D_;
    const bool vz = (z == 2);
    const bf16* A  = vz ? Xz : Wz;             // MFMA-A operand (m rows)
    const bf16* Bm = vz ? Wz : Xz;             // MFMA-B operand (n rows)

    const int lane = threadIdx.x & 63;
    const int wave = threadIdx.x >> 6;
    const int lc = lane & 15;
    const int lg = lane >> 4;
    const int gAb = vz ? 2 * mt : 2 * nt;      // block A-group base (2 groups)
    const int gBb = vz ? 2 * nt : 2 * mt;      // block B-group base (2 groups)
    const int aIdx = wave >> 1;                // this wave's A group (0/1)
    const int bIdx = wave & 1;                 // this wave's B group (0/1)
    const int gA = gAb + aIdx;
    const int gB = gBb + bIdx;

    __shared__ bf16 Ab[3][4096];               // ring-3: 2 groups x 4 t x 512
    __shared__ bf16 Bb[3][4096];

    // stage kk-step s: 16 chunks of 1 KB, 4 per wave, linear async16 copy
    auto stage = [&](int s) {
        const int k0 = s >> 1, kk = s & 1;
        bf16* ad = Ab[s % 3];
        bf16* bd = Bb[s % 3];
        #pragma unroll
        for (int i = 0; i < 4; ++i) {
            const int c  = wave * 4 + i;       // 0..15
            const int gx = (c >> 2) & 1;
            const int t  = c & 3;
            const bf16* srcb = (c < 8) ? A + fragbase(gAb + gx, k0, kk, t)
                                       : Bm + fragbase(gBb + gx, k0, kk, t);
            bf16* dstb = ((c < 8) ? ad : bd) + (gx * 4 + t) * 512;
            async16(srcb + (size_t)lane * 8, dstb + (size_t)lane * 8);
        }
    };

    f32x4 acc[4][4] = {};

    stage(0); stage(1);                        // prologue: 8 loads in flight

    for (int s = 0; s < 16; ++s) {
        // own tile-s loads retired; tile s+1 (4 loads) stays in flight
        if (s + 1 < 16) asm volatile("s_waitcnt vmcnt(4)" ::: "memory");
        else            asm volatile("s_waitcnt vmcnt(0)" ::: "memory");
        __builtin_amdgcn_s_barrier();          // all waves' stage(s) visible
        if (s + 2 < 16) stage(s + 2);          // overwrites buf (s-1)%3: safe

        const bf16* ab = Ab[s % 3] + aIdx * 2048;
        const bf16* bb = Bb[s % 3] + bIdx * 2048;
        bf16x8 af[4], bfm[4];
        #pragma unroll
        for (int t = 0; t < 4; ++t) {
            af[t]  = ldg8(ab + t * 512 + (size_t)lane * 8);
            bfm[t] = ldg8(bb + t * 512 + (size_t)lane * 8);
        }
        #pragma unroll
        for (int mi = 0; mi < 4; ++mi)
            #pragma unroll
            for (int ni = 0; ni < 4; ++ni)
                acc[mi][ni] = MFMA16(af[mi], bfm[ni], acc[mi][ni]);
    }

    if (z < 2) {
        bf16* Y = qkv + (size_t)z * M_ * D_;
        const float sc = (z == 0) ? 0.125f * 1.4426950408889634f : 1.0f;
        #pragma unroll
        for (int mi = 0; mi < 4; ++mi)
            #pragma unroll
            for (int ni = 0; ni < 4; ++ni) {
                const int d = gA * 64 + mi * 16 + lg * 4;
                const int s = gB * 64 + ni * 16 + lc;
                bf16x4 v;
                #pragma unroll
                for (int r = 0; r < 4; ++r) v[r] = (bf16)(acc[mi][ni][r] * sc);
                const size_t oidx =
                    ((((size_t)(s >> 11) * H_ + (d >> 6)) * S_
                      + (s & (S_ - 1))) << 6) + (d & 63);
                *reinterpret_cast<bf16x4*>(&Y[oidx]) = v;
            }
    } else {
        bf16* Y = qkv + (size_t)2 * M_ * D_;
        #pragma unroll
        for (int mi = 0; mi < 4; ++mi)
            #pragma unroll
            for (int ni = 0; ni < 4; ++ni) {
                const int s = gA * 64 + mi * 16 + lg * 4;
                const int d = gB * 64 + ni * 16 + lc;
                bf16x4 v;
                #pragma unroll
                for (int r = 0; r < 4; ++r) v[r] = (bf16)acc[mi][ni][r];
                const size_t oidx =
                    ((((size_t)(s >> 11)) * H_ + (d >> 6)) << 17)
                    + (size_t)(d & 63) * S_ + (s & (S_ - 1));
                *reinterpret_cast<bf16x4*>(&Y[oidx]) = v;
            }
    }
}

// ---------------------------------------------------------------------------
// Output projection with LDS RING (r6): same conversion as gemm_qkv.
// Block = 64 s x 128 d, 4 waves. Per kk-step: stage 12 KB (A=Wo 2 groups =
// 8 chunks, B=ctx 1 group = 4 chunks; 3 chunks/wave), counted vmcnt(3),
// ring-3 (36 KB). Each wave reads 2 A-frags + 4 B-frags, 8 MFMA.
// Grid 512 (2 blocks/CU), XCD swizzle on the s-stripe.
// ---------------------------------------------------------------------------
__global__ __launch_bounds__(256) void gemm_out(
    const bf16* __restrict__ CtxF, const bf16* __restrict__ WoF,
    float* __restrict__ out)
{
    const int bx  = blockIdx.x;
    const int xcd = bx & 7;
    const int idx = bx >> 3;
    const int mt  = xcd + 8 * (idx & 15);      // 0..127: ctx 64-row s-group
    const int nt  = idx >> 4;                  // 0..3: Wo 128-row d-tile

    const int lane = threadIdx.x & 63;
    const int wave = threadIdx.x >> 6;
    const int lc = lane & 15;
    const int lg = lane >> 4;
    const int gA = 2 * nt + (wave >> 1);       // Wo 64-row group
    const int tA = (wave & 1) * 2;             // 2 d-tiles per wave
    const int gB = mt;                         // ctx s-group (shared by block)

    __shared__ bf16 Ab[3][4096];               // 2 Wo groups x 4 t x 512
    __shared__ bf16 Bb[3][2048];               // 1 ctx group x 4 t x 512

    auto stage = [&](int s) {
        const int k0 = s >> 1, kk = s & 1;
        bf16* ad = Ab[s % 3];
        bf16* bd = Bb[s % 3];
        #pragma unroll
        for (int i = 0; i < 3; ++i) {
            const int c = wave * 3 + i;        // 0..11
            if (c < 8) {
                const int gx = c >> 2, t = c & 3;
                async16(WoF + fragbase(2 * nt + gx, k0, kk, t) + (size_t)lane * 8,
                        ad + (gx * 4 + t) * 512 + (size_t)lane * 8);
            } else {
                const int t = c - 8;
                async16(CtxF + fragbase(gB, k0, kk, t) + (size_t)lane * 8,
                        bd + t * 512 + (size_t)lane * 8);
            }
        }
    };

    f32x4 acc[2][4] = {};

    stage(0); stage(1);                        // prologue: 6 loads in flight

    for (int s = 0; s < 16; ++s) {
        if (s + 1 < 16) asm volatile("s_waitcnt vmcnt(3)" ::: "memory");
        else            asm volatile("s_waitcnt vmcnt(0)" ::: "memory");
        __builtin_amdgcn_s_barrier();
        if (s + 2 < 16) stage(s + 2);

        const bf16* ab = Ab[s % 3] + (wave >> 1) * 2048;
        const bf16* bb = Bb[s % 3];
        bf16x8 af[2], bfm[4];
        #pragma unroll
        for (int ai = 0; ai < 2; ++ai)
            af[ai] = ldg8(ab + (tA + ai) * 512 + (size_t)lane * 8);
        #pragma unroll
        for (int t = 0; t < 4; ++t)
            bfm[t] = ldg8(bb + t * 512 + (size_t)lane * 8);
        #pragma unroll
        for (int ai = 0; ai < 2; ++ai)
            #pragma unroll
            for (int ni = 0; ni < 4; ++ni)
                acc[ai][ni] = MFMA16(af[ai], bfm[ni], acc[ai][ni]);
    }

    #pragma unroll
    for (int ai = 0; ai < 2; ++ai)
        #pragma unroll
        for (int ni = 0; ni < 4; ++ni) {
            const int d = gA * 64 + (tA + ai) * 16 + lg * 4;
            const int s = gB * 64 + ni * 16 + lc;
            *reinterpret_cast<f32x4*>(&out[(size_t)s * D_ + d]) = acc[ai][ni];
        }
}

// ---------------------------------------------------------------------------
// Build the PV B-fragment IN REGISTERS from the QK^T score layout.
// Scores: lane(lg,lc) holds P[k=16t+4lg+r][q=lc] (r=0..3) per t.
// bf16-pack pairs into dwords, then one permlane16_swap per dword pair:
// dst.row[2k+1] <-> src.row[2k]. Result rows hold k-chunks in order
// sigma=[0,2,1,3]; V's LDS staging is source-permuted with the same sigma
// (T21: per-lane global src permutation, linear LDS, linear b128 reads).
// Must be the BUILTIN, not inline asm (hazard recognizer).
// ---------------------------------------------------------------------------
__device__ __forceinline__ bf16x8 pfrag(const f32x4 a, const f32x4 b) {
    union U4 { bf16x4 v; unsigned int u[2]; };
    U4 pa, pb;
    #pragma unroll
    for (int r = 0; r < 4; ++r) { pa.v[r] = (bf16)a[r]; pb.v[r] = (bf16)b[r]; }
    auto r0 = __builtin_amdgcn_permlane16_swap(pa.u[0], pb.u[0], false, false);
    auto r1 = __builtin_amdgcn_permlane16_swap(pa.u[1], pb.u[1], false, false);
    union U8 { unsigned int u[4]; bf16x8 v; } out;
    out.u[0] = r0[0]; out.u[1] = r1[0]; out.u[2] = r0[1]; out.u[3] = r1[1];
    return out.v;
}

// ---------------------------------------------------------------------------
// Causal flash attention (unchanged from r5; known LDS-BW-bound at ~40 µs:
// per-iter wall 3.0k cyc == 16 waves x 16 ds_read_b128 x 12 cyc LDS port
// time — the k-split read-halving is the next lever if attn becomes top).
// 8-wave paired-tile blocks, 4-deep K/V ring, raw s_barrier + counted vmcnt.
// ---------------------------------------------------------------------------
__global__ __launch_bounds__(512, 4) void attn(
    const bf16* __restrict__ QKV, bf16* __restrict__ CtxF)
{
    const int bx = blockIdx.x;
    const int bh = (bx & 7) * 4 + ((bx >> 3) & 3);   // same-XCD bh grouping
    const int pi = bx >> 5;                           // 0..15
    const int b = bh >> 3, h = bh & 7;
    const size_t plane = (size_t)S_ * DK_;
    const bf16* Q  = QKV + (size_t)bh * plane;
    const bf16* Kp = QKV + (size_t)(B_ * H_) * plane + (size_t)bh * plane;
    const bf16* Vt = QKV + 2 * (size_t)(B_ * H_) * plane + (size_t)bh * plane;

    const int lane = threadIdx.x & 63;
    const int wave = threadIdx.x >> 6;   // 0..7
    const int wv   = wave & 3;           // row-group within tile
    const int half = wave >> 2;          // 0 -> hi tile, 1 -> lo tile
    const int lc = lane & 15;
    const int lg = lane >> 4;
    const int sg = ((lg & 1) << 1) | (lg >> 1);      // sigma(lg): swap 1<->2
    const int srow = wv * 16 + lc;
    const int mrow = wv * 16 + lc;       // q row within tile for this lane

    __shared__ bf16 Ks[4][64 * 64];      // 4-deep ring, 32 KB
    __shared__ bf16 Vs[4][64 * 64];      // 4-deep ring, 32 KB

    const int lo = pi;
    const int hi = 31 - pi;              // hi >= 16 always
    const int myq = half ? lo : hi;      // this wave's q-tile

    const int qR = myq * 64 + mrow;
    bf16x8 qf0 = ldg8(Q + (size_t)qR * DK_ + lg * 8);
    bf16x8 qf1 = ldg8(Q + (size_t)qR * DK_ + 32 + lg * 8);

    f32x4 accO[4] = {};
    float li = 0.f;

    // Staging split: waves 0-3 stage K, waves 4-7 stage V (2 async16/wave).
    auto stage = [&](int n) {
        const int kn = n * 64;
        if (half == 0) {
            bf16* kd = Ks[n & 3];
            #pragma unroll
            for (int i = 0; i < 2; ++i) {
                const int kc = i * 4 + lg;
                async16(Kp + (size_t)(kn + srow) * DK_ + kc * 8,
                        kd + (i * 256 + wv * 64) * 8);
            }
        } else {
            bf16* vd = Vs[n & 3];
            #pragma unroll
            for (int i = 0; i < 2; ++i) {
                const int kcv = i * 4 + sg;  // sigma-permuted V source
                async16(Vt + (size_t)srow * S_ + kn + kcv * 8,
                        vd + (i * 256 + wv * 64) * 8);
            }
        }
    };

    stage(0); stage(1); stage(2);        // prologue: 6 loads in flight / wave

    for (int j = 0; j <= hi; ++j) {
        // Counted wait: this wave's tile-j loads retired; j+1, j+2 in flight.
        if (j + 2 <= hi)      asm volatile("s_waitcnt vmcnt(4)" ::: "memory");
        else if (j + 1 <= hi) asm volatile("s_waitcnt vmcnt(2)" ::: "memory");
        else                  asm volatile("s_waitcnt vmcnt(0)" ::: "memory");
        __builtin_amdgcn_s_barrier();    // raw barrier: no vmcnt drain
        if (j + 3 <= hi) stage(j + 3);   // overwrites buf (j-1)&3: safe

        if (j <= myq) {                  // lo-tile waves idle (stage-only) past lo
            const bf16* ks = Ks[j & 3];
            const bf16* vs = Vs[j & 3];

            bf16x8 kf0[4], kf1[4], vf0[4], vf1[4];
            #pragma unroll
            for (int t = 0; t < 4; ++t) {
                kf0[t] = ldg8(&ks[(t * 64 + lane) * 8]);
                kf1[t] = ldg8(&ks[(256 + t * 64 + lane) * 8]);
                vf0[t] = ldg8(&vs[(t * 64 + lane) * 8]);
                vf1[t] = ldg8(&vs[(256 + t * 64 + lane) * 8]);
            }

            f32x4 st[4];
            #pragma unroll
            for (int t = 0; t < 4; ++t) {
                f32x4 zz = {};
                zz = MFMA16(kf0[t], qf0, zz);
                st[t] = MFMA16(kf1[t], qf1, zz);
            }
            float rs = 0.f;
            if (j == myq) {              // diagonal tile: causal mask
                #pragma unroll
                for (int t = 0; t < 4; ++t)
                    #pragma unroll
                    for (int r = 0; r < 4; ++r) {
                        const int kl = t * 16 + lg * 4 + r;
                        const float pv = EXP2((kl <= mrow) ? st[t][r] : -1e30f);
                        st[t][r] = pv;
                        rs += pv;
                    }
            } else {
                #pragma unroll
                for (int t = 0; t < 4; ++t)
                    #pragma unroll
                    for (int r = 0; r < 4; ++r) {
                        const float pv = EXP2(st[t][r]);
                        st[t][r] = pv;
                        rs += pv;
                    }
            }
            li += rs;

            const bf16x8 p0 = pfrag(st[0], st[1]);   // k 0..31  (sigma order)
            const bf16x8 p1 = pfrag(st[2], st[3]);   // k 32..63 (sigma order)

            #pragma unroll
            for (int t = 0; t < 4; ++t) {
                accO[t] = MFMA16(vf0[t], p0, accO[t]);
                accO[t] = MFMA16(vf1[t], p1, accO[t]);
            }
        }
    }

    // ---- epilogue: frag-major ctx via per-wave LDS transpose ---------------
    li += __shfl_xor(li, 16); li += __shfl_xor(li, 32);
    const float rl = 1.0f / li;
    __syncthreads();                     // full drain once; reuse Ks
    bf16* T = &Ks[0][0] + wave * 1280;   // 8 waves x 16x72 (padded) buffers

    #pragma unroll
    for (int t = 0; t < 4; ++t) {
        bf16x4 ov;
        #pragma unroll
        for (int r = 0; r < 4; ++r) ov[r] = (bf16)(accO[t][r] * rl);
        *reinterpret_cast<bf16x4*>(&T[lc * 72 + t * 16 + lg * 4]) = ov;
    }
    // wave-synchronous LDS: compiler inserts lgkmcnt before these reads
    #pragma unroll
    for (int kk = 0; kk < 2; ++kk) {
        bf16x8 o8 = ldg8(&T[lc * 72 + kk * 32 + lg * 8]);
        *reinterpret_cast<bf16x8*>(
            &CtxF[fragbase(b * 32 + myq, h, kk, wv) + (size_t)lane * 8]) = o8;
    }
}

extern "C" void kernel_launch(void* const* d_in, const int* in_sizes, int n_in,
                              void* d_out, int out_size, void* d_ws, size_t ws_size,
                              hipStream_t stream)
{
    float* out = (float*)d_out;

    bf16* Xf   = (bf16*)d_ws;                         // [3][M_*D_] frag-major
    bf16* Wf   = Xf + (size_t)3 * M_ * D_;            // [4][D_*D_] frag-major
    bf16* qkv  = Wf + (size_t)4 * D_ * D_;            // Q,K [bh][s][64]; V^T [bh][d][s]
    bf16* ctxF = qkv + (size_t)3 * M_ * D_;           // [M_*D_] frag-major

    cvt_all<<<6656, 256, 0, stream>>>(
        (const float*)d_in[0], (const float*)d_in[1], (const float*)d_in[2],
        (const float*)d_in[3], (const float*)d_in[4], (const float*)d_in[5],
        (const float*)d_in[6], Xf);

    gemm_qkv<<<dim3(768), 256, 0, stream>>>(Xf, Wf, qkv);
    attn<<<dim3(512), 512, 0, stream>>>(qkv, ctxF);
    gemm_out<<<dim3(512), 256, 0, stream>>>(ctxF, Wf + (size_t)3 * D_ * D_, out);
}